// Round 2
// baseline (461.177 us; speedup 1.0000x reference)
//
#include <hip/hip_runtime.h>

#define NN 1024
#define FF 64
#define NBT 64
#define INV_LN2 1.44269504088896f

typedef float f32x4 __attribute__((ext_vector_type(4)));
typedef short s16x8 __attribute__((ext_vector_type(8)));
typedef unsigned u32x4 __attribute__((ext_vector_type(4)));

__device__ __forceinline__ short f2bf(float f) {
    unsigned u = __builtin_bit_cast(unsigned, f);
    u = (u + 0x7FFFu + ((u >> 16) & 1u)) >> 16;
    return (short)u;
}

// Kernel 1: Wh = h @ W (fp32 compute). Outputs:
//   WhT  bf16  [bt][c][j]   (transposed so k2 B-fragments are contiguous in j)
//   s1,s2 fp32 [bt][j]      (Wh.a1, Wh.a2) PRE-SCALED by 1/ln2 so k2 can use
//   raw v_exp_f32 (2^x). leaky_relu commutes with positive scaling.
__global__ __launch_bounds__(256) void k1(const float* __restrict__ h,
                                          const float* __restrict__ W,
                                          const float* __restrict__ a,
                                          short* __restrict__ WhT,
                                          float* __restrict__ s1g,
                                          float* __restrict__ s2g) {
    __shared__ float Wl[64 * 64];   // [k][c]
    __shared__ float al[128];
    __shared__ float s1sh[128], s2sh[128];
    const int blk = blockIdx.x;
    const int bt = blk >> 3;
    const int rbase = (blk & 7) * 128;
    const int t = threadIdx.x;

    for (int i = t; i < 1024; i += 256)
        ((f32x4*)Wl)[i] = ((const f32x4*)W)[i];
    if (t < 32) ((f32x4*)al)[t] = ((const f32x4*)a)[t];
    __syncthreads();

    const int row = rbase + (t & 127);
    const int half = t >> 7;           // 0: c 0..31, 1: c 32..63
    const float* hrow = h + ((size_t)bt * NN + row) * FF;
    float hv[64];
#pragma unroll
    for (int i = 0; i < 16; i++)
        ((f32x4*)hv)[i] = ((const f32x4*)hrow)[i];

    float s1 = 0.f, s2 = 0.f;
    short* wt = WhT + (size_t)bt * FF * NN + row;
#pragma unroll
    for (int cgi = 0; cgi < 8; cgi++) {
        const int cg = half * 8 + cgi;       // float4 group of columns
        f32x4 acc = {0.f, 0.f, 0.f, 0.f};
#pragma unroll
        for (int k = 0; k < 64; k++) {
            f32x4 w4 = ((const f32x4*)Wl)[k * 16 + cg];  // broadcast read
            acc += hv[k] * w4;
        }
        const int c0 = cg * 4;
        s1 += acc.x * al[c0] + acc.y * al[c0 + 1] + acc.z * al[c0 + 2] + acc.w * al[c0 + 3];
        s2 += acc.x * al[64 + c0] + acc.y * al[64 + c0 + 1] + acc.z * al[64 + c0 + 2] + acc.w * al[64 + c0 + 3];
        wt[(size_t)(c0 + 0) * NN] = f2bf(acc.x);
        wt[(size_t)(c0 + 1) * NN] = f2bf(acc.y);
        wt[(size_t)(c0 + 2) * NN] = f2bf(acc.z);
        wt[(size_t)(c0 + 3) * NN] = f2bf(acc.w);
    }
    if (half == 1) { s1sh[t & 127] = s1; s2sh[t & 127] = s2; }
    __syncthreads();
    if (half == 0) {
        s1g[bt * NN + row] = (s1 + s1sh[t]) * INV_LN2;
        s2g[bt * NN + row] = (s2 + s2sh[t]) * INV_LN2;
    }
}

// Kernel 2: masked-softmax attention + P @ Wh via bf16 MFMA, + elu.
// grid 1024 = 64 batches x 16 row-tiles (64 rows). 256 threads = 4 waves.
// Barrier-free main loop; per-lane A-fragment (P) computed in registers
// (row = wv*16 + (l&15), j = jt*32 + (l>>4)*8 + u — the 16x16x32 A layout).
// Depth-2 register prefetch (ping-pong A/B stages) covers HBM latency on adj.
// Row-sums come from a 5th MFMA with B = ones: accR[e] = rowsum(q*4+e),
// exactly the rows this lane's C-fragment holds — no shuffles, and the
// softmax numerator/denominator use the same bf16-rounded P.
__global__ __launch_bounds__(256, 4) void k2(const int* __restrict__ adj,
                                             const short* __restrict__ WhT,
                                             const float* __restrict__ s1g,
                                             const float* __restrict__ s2g,
                                             float* __restrict__ out) {
    __shared__ float s2l[NN];

    const int bx = blockIdx.x;
    const int bt = bx >> 4;
    const int ibase = (bx & 15) * 64;
    const int t = threadIdx.x;
    const int wv = t >> 6;
    const int l = t & 63;
    const int m = l & 15;      // row within wave tile / B column
    const int q = l >> 4;      // k-group (j octet)

    // stage the full s2 row for this batch (reused by all 32 j-tiles)
    ((f32x4*)s2l)[t] = ((const f32x4*)(s2g + (size_t)bt * NN))[t];

    const int row = ibase + wv * 16 + m;
    const float s1v = s1g[bt * NN + row];

    const int* adjp = adj + ((size_t)bt * NN + row) * NN + q * 8;
    const short* whp = WhT + (size_t)bt * FF * NN + (size_t)m * NN + q * 8;

    f32x4 acc0 = {0.f, 0.f, 0.f, 0.f};
    f32x4 acc1 = {0.f, 0.f, 0.f, 0.f};
    f32x4 acc2 = {0.f, 0.f, 0.f, 0.f};
    f32x4 acc3 = {0.f, 0.f, 0.f, 0.f};
    f32x4 accR = {0.f, 0.f, 0.f, 0.f};
    const s16x8 ones = {0x3F80, 0x3F80, 0x3F80, 0x3F80, 0x3F80, 0x3F80, 0x3F80, 0x3F80};

#define LDT(J, A0, A1, B0, B1, B2, B3) do {            \
        const int _o = ((J) < 32 ? (J) : 31) * 32;     \
        A0 = *(const int4*)(adjp + _o);                \
        A1 = *(const int4*)(adjp + _o + 4);            \
        B0 = *(const s16x8*)(whp + _o);                \
        B1 = *(const s16x8*)(whp + 16 * NN + _o);      \
        B2 = *(const s16x8*)(whp + 32 * NN + _o);      \
        B3 = *(const s16x8*)(whp + 48 * NN + _o);      \
    } while (0)

    auto compute = [&](int jt, int4 ca0, int4 ca1,
                       s16x8 cb0, s16x8 cb1, s16x8 cb2, s16x8 cb3) {
        f32x4 s2a = *(const f32x4*)&s2l[jt * 32 + q * 8];
        f32x4 s2b = *(const f32x4*)&s2l[jt * 32 + q * 8 + 4];
        const int aj[8] = {ca0.x, ca0.y, ca0.z, ca0.w, ca1.x, ca1.y, ca1.z, ca1.w};
        const float sv[8] = {s2a.x, s2a.y, s2a.z, s2a.w, s2b.x, s2b.y, s2b.z, s2b.w};
        float p[8];
#pragma unroll
        for (int u = 0; u < 8; u++) {
            float e = s1v + sv[u];          // already in log2 domain
            e = fmaxf(e, 0.2f * e);         // leaky_relu (scale-commutes)
            e = fminf(e, 86.0f);            // paranoia clamp (== old 60/ln2)
            float pe = exp2f(e);            // v_exp_f32
            p[u] = (aj[u] > 0) ? pe : 0.f;
        }
        unsigned w0, w1, w2, w3;            // RNE pack, identical to manual round
        asm("v_cvt_pk_bf16_f32 %0, %1, %2" : "=v"(w0) : "v"(p[0]), "v"(p[1]));
        asm("v_cvt_pk_bf16_f32 %0, %1, %2" : "=v"(w1) : "v"(p[2]), "v"(p[3]));
        asm("v_cvt_pk_bf16_f32 %0, %1, %2" : "=v"(w2) : "v"(p[4]), "v"(p[5]));
        asm("v_cvt_pk_bf16_f32 %0, %1, %2" : "=v"(w3) : "v"(p[6]), "v"(p[7]));
        u32x4 wq = {w0, w1, w2, w3};
        s16x8 af = __builtin_bit_cast(s16x8, wq);

        acc0 = __builtin_amdgcn_mfma_f32_16x16x32_bf16(af, cb0, acc0, 0, 0, 0);
        acc1 = __builtin_amdgcn_mfma_f32_16x16x32_bf16(af, cb1, acc1, 0, 0, 0);
        acc2 = __builtin_amdgcn_mfma_f32_16x16x32_bf16(af, cb2, acc2, 0, 0, 0);
        acc3 = __builtin_amdgcn_mfma_f32_16x16x32_bf16(af, cb3, acc3, 0, 0, 0);
        accR = __builtin_amdgcn_mfma_f32_16x16x32_bf16(af, ones, accR, 0, 0, 0);
    };

    int4 a0A, a1A; s16x8 b0A, b1A, b2A, b3A;
    int4 a0B, a1B; s16x8 b0B, b1B, b2B, b3B;

    __syncthreads();   // s2l ready (only barrier; before prefetch so the
                       // barrier's vmcnt-drain doesn't flush our pipeline)

    LDT(0, a0A, a1A, b0A, b1A, b2A, b3A);
    LDT(1, a0B, a1B, b0B, b1B, b2B, b3B);

    for (int jt = 0; jt < 32; jt += 2) {
        {   // tile jt: snapshot stage A, issue loads for jt+2, then compute
            int4 ta0 = a0A, ta1 = a1A;
            s16x8 t0 = b0A, t1 = b1A, t2 = b2A, t3 = b3A;
            LDT(jt + 2, a0A, a1A, b0A, b1A, b2A, b3A);
            compute(jt, ta0, ta1, t0, t1, t2, t3);
        }
        {   // tile jt+1: snapshot stage B, issue loads for jt+3, then compute
            int4 ta0 = a0B, ta1 = a1B;
            s16x8 t0 = b0B, t1 = b1B, t2 = b2B, t3 = b3B;
            LDT(jt + 3, a0B, a1B, b0B, b1B, b2B, b3B);
            compute(jt + 1, ta0, ta1, t0, t1, t2, t3);
        }
    }
#undef LDT

    float rinv[4];
#pragma unroll
    for (int e = 0; e < 4; e++)
        rinv[e] = accR[e] > 0.f ? 1.f / accR[e] : 0.f;

    float* outp = out + ((size_t)bt * NN + ibase + wv * 16 + q * 4) * FF + m;
#pragma unroll
    for (int e = 0; e < 4; e++) {
        float v0 = acc0[e] * rinv[e];
        float v1 = acc1[e] * rinv[e];
        float v2 = acc2[e] * rinv[e];
        float v3 = acc3[e] * rinv[e];
        v0 = v0 > 0.f ? v0 : expm1f(v0);
        v1 = v1 > 0.f ? v1 : expm1f(v1);
        v2 = v2 > 0.f ? v2 : expm1f(v2);
        v3 = v3 > 0.f ? v3 : expm1f(v3);
        float* o = outp + (size_t)e * FF;
        o[0]  = v0;
        o[16] = v1;
        o[32] = v2;
        o[48] = v3;
    }
}

extern "C" void kernel_launch(void* const* d_in, const int* in_sizes, int n_in,
                              void* d_out, int out_size, void* d_ws, size_t ws_size,
                              hipStream_t stream) {
    const float* h  = (const float*)d_in[0];
    const int*  adj = (const int*)d_in[1];
    const float* W  = (const float*)d_in[2];
    const float* a  = (const float*)d_in[3];
    float* out = (float*)d_out;

    short* WhT = (short*)d_ws;                                      // 64*64*1024*2 = 8 MB
    float* s1  = (float*)((char*)d_ws + (size_t)NBT * FF * NN * 2); // 256 KB
    float* s2  = s1 + NBT * NN;                                     // 256 KB

    k1<<<512, 256, 0, stream>>>(h, W, a, WhT, s1, s2);
    k2<<<1024, 256, 0, stream>>>(adj, WhT, s1, s2, out);
}

// Round 3
// 458.341 us; speedup vs baseline: 1.0062x; 1.0062x over previous
//
#include <hip/hip_runtime.h>

#define NN 1024
#define FF 64
#define NBT 64
#define INV_LN2 1.44269504088896f

typedef float f32x4 __attribute__((ext_vector_type(4)));
typedef short s16x8 __attribute__((ext_vector_type(8)));

__device__ __forceinline__ short f2bf(float f) {
    unsigned u = __builtin_bit_cast(unsigned, f);
    u = (u + 0x7FFFu + ((u >> 16) & 1u)) >> 16;
    return (short)u;
}

// Kernel 1: Wh = h @ W (fp32 compute). Outputs:
//   WhT  bf16  [bt][c][j]   (transposed so k2 B-fragments are contiguous in j)
//   s1,s2 fp32 [bt][j]      (Wh.a1, Wh.a2) PRE-SCALED by 1/ln2 so k2 can use
//   raw v_exp_f32 (2^x). leaky_relu commutes with positive scaling.
__global__ __launch_bounds__(256) void k1(const float* __restrict__ h,
                                          const float* __restrict__ W,
                                          const float* __restrict__ a,
                                          short* __restrict__ WhT,
                                          float* __restrict__ s1g,
                                          float* __restrict__ s2g) {
    __shared__ float Wl[64 * 64];   // [k][c]
    __shared__ float al[128];
    __shared__ float s1sh[128], s2sh[128];
    const int blk = blockIdx.x;
    const int bt = blk >> 3;
    const int rbase = (blk & 7) * 128;
    const int t = threadIdx.x;

    for (int i = t; i < 1024; i += 256)
        ((f32x4*)Wl)[i] = ((const f32x4*)W)[i];
    if (t < 32) ((f32x4*)al)[t] = ((const f32x4*)a)[t];
    __syncthreads();

    const int row = rbase + (t & 127);
    const int half = t >> 7;           // 0: c 0..31, 1: c 32..63
    const float* hrow = h + ((size_t)bt * NN + row) * FF;
    float hv[64];
#pragma unroll
    for (int i = 0; i < 16; i++)
        ((f32x4*)hv)[i] = ((const f32x4*)hrow)[i];

    float s1 = 0.f, s2 = 0.f;
    short* wt = WhT + (size_t)bt * FF * NN + row;
#pragma unroll
    for (int cgi = 0; cgi < 8; cgi++) {
        const int cg = half * 8 + cgi;       // float4 group of columns
        f32x4 acc = {0.f, 0.f, 0.f, 0.f};
#pragma unroll
        for (int k = 0; k < 64; k++) {
            f32x4 w4 = ((const f32x4*)Wl)[k * 16 + cg];  // broadcast read
            acc += hv[k] * w4;
        }
        const int c0 = cg * 4;
        s1 += acc.x * al[c0] + acc.y * al[c0 + 1] + acc.z * al[c0 + 2] + acc.w * al[c0 + 3];
        s2 += acc.x * al[64 + c0] + acc.y * al[64 + c0 + 1] + acc.z * al[64 + c0 + 2] + acc.w * al[64 + c0 + 3];
        wt[(size_t)(c0 + 0) * NN] = f2bf(acc.x);
        wt[(size_t)(c0 + 1) * NN] = f2bf(acc.y);
        wt[(size_t)(c0 + 2) * NN] = f2bf(acc.z);
        wt[(size_t)(c0 + 3) * NN] = f2bf(acc.w);
    }
    if (half == 1) { s1sh[t & 127] = s1; s2sh[t & 127] = s2; }
    __syncthreads();
    if (half == 0) {
        s1g[bt * NN + row] = (s1 + s1sh[t]) * INV_LN2;
        s2g[bt * NN + row] = (s2 + s2sh[t]) * INV_LN2;
    }
}

// Kernel 2: masked-softmax attention + P @ Wh via bf16 MFMA, + elu.
// grid 2048 = 64 batches x 32 row-tiles (32 rows). 256 threads = 4 waves:
//   wave wv: pr = wv>>1 picks the 16-row sub-tile, jh = wv&1 picks the
//   column half (j-split doubles wave count to 8192 = 32 waves/CU to cover
//   HBM latency on the adj stream -- round-2 counters showed latency-bound:
//   13% HBM, 16% VALU, 38% occupancy).
// Per-lane A-fragment (P) in registers (row = l&15, j = jt*32+(l>>4)*8+u,
// the 16x16x32 A layout). Depth-1 register rotation prefetch (round-1's
// proven form; NO inline asm -- the cvt_pk asm was a known -37% trap).
// Rowsum via 5th MFMA with B = ones. Epilogue: jh=1 waves push partial
// acc/rowsum through LDS, jh=0 waves reduce + normalize + elu + store.
__global__ __launch_bounds__(256, 8) void k2(const int* __restrict__ adj,
                                             const short* __restrict__ WhT,
                                             const float* __restrict__ s1g,
                                             const float* __restrict__ s2g,
                                             float* __restrict__ out) {
    __shared__ float s2l[NN];
    __shared__ __align__(16) float xch[2][64][24];   // stride 24 floats = 96B (16B-aligned)

    const int bx = blockIdx.x;
    const int bt = bx >> 5;
    const int rbase = (bx & 31) * 32;
    const int t = threadIdx.x;
    const int wv = t >> 6;
    const int pr = wv >> 1;    // row sub-tile (0: rows 0-15, 1: rows 16-31)
    const int jh = wv & 1;     // column half (0: j 0-511, 1: j 512-1023)
    const int l = t & 63;
    const int m = l & 15;      // A row / B column
    const int q = l >> 4;      // k-group (j octet)

    // stage the full s2 row for this batch (shared by all 4 waves)
    ((f32x4*)s2l)[t] = ((const f32x4*)(s2g + (size_t)bt * NN))[t];

    const int row = rbase + pr * 16 + m;
    const float s1v = s1g[bt * NN + row];

    const int jt0 = jh * 16;
    const int jtN = jt0 + 15;
    const int* adjp = adj + ((size_t)bt * NN + row) * NN + q * 8;
    const short* whp = WhT + (size_t)bt * FF * NN + (size_t)m * NN + q * 8;

    f32x4 acc0 = {0.f, 0.f, 0.f, 0.f};
    f32x4 acc1 = {0.f, 0.f, 0.f, 0.f};
    f32x4 acc2 = {0.f, 0.f, 0.f, 0.f};
    f32x4 acc3 = {0.f, 0.f, 0.f, 0.f};
    f32x4 accR = {0.f, 0.f, 0.f, 0.f};
    const s16x8 ones = {0x3F80, 0x3F80, 0x3F80, 0x3F80, 0x3F80, 0x3F80, 0x3F80, 0x3F80};

    // prefetch first tile of this wave's column half
    int4 ca0 = *(const int4*)(adjp + jt0 * 32);
    int4 ca1 = *(const int4*)(adjp + jt0 * 32 + 4);
    s16x8 cb0 = *(const s16x8*)(whp + jt0 * 32);
    s16x8 cb1 = *(const s16x8*)(whp + 16 * NN + jt0 * 32);
    s16x8 cb2 = *(const s16x8*)(whp + 32 * NN + jt0 * 32);
    s16x8 cb3 = *(const s16x8*)(whp + 48 * NN + jt0 * 32);

    __syncthreads();   // s2l ready

    for (int jt = jt0; jt <= jtN; jt++) {
        const int jn = (jt < jtN ? jt + 1 : jtN) * 32;   // dup last: harmless
        int4 na0 = *(const int4*)(adjp + jn);
        int4 na1 = *(const int4*)(adjp + jn + 4);
        s16x8 nb0 = *(const s16x8*)(whp + jn);
        s16x8 nb1 = *(const s16x8*)(whp + 16 * NN + jn);
        s16x8 nb2 = *(const s16x8*)(whp + 32 * NN + jn);
        s16x8 nb3 = *(const s16x8*)(whp + 48 * NN + jn);

        // P = adj ? exp2(leaky(s1+s2)) : 0   (log2-domain, no max-subtraction)
        f32x4 s2a = *(const f32x4*)&s2l[jt * 32 + q * 8];
        f32x4 s2b = *(const f32x4*)&s2l[jt * 32 + q * 8 + 4];
        const int aj[8] = {ca0.x, ca0.y, ca0.z, ca0.w, ca1.x, ca1.y, ca1.z, ca1.w};
        const float sv[8] = {s2a.x, s2a.y, s2a.z, s2a.w, s2b.x, s2b.y, s2b.z, s2b.w};
        s16x8 af;
#pragma unroll
        for (int u = 0; u < 8; u++) {
            float e = s1v + sv[u];
            e = fmaxf(e, 0.2f * e);         // leaky_relu (scale-commutes)
            e = fminf(e, 86.0f);            // paranoia clamp, never active
            float pe = exp2f(e);            // v_exp_f32
            float p = (aj[u] > 0) ? pe : 0.f;
            af[u] = f2bf(p);
        }

        acc0 = __builtin_amdgcn_mfma_f32_16x16x32_bf16(af, cb0, acc0, 0, 0, 0);
        acc1 = __builtin_amdgcn_mfma_f32_16x16x32_bf16(af, cb1, acc1, 0, 0, 0);
        acc2 = __builtin_amdgcn_mfma_f32_16x16x32_bf16(af, cb2, acc2, 0, 0, 0);
        acc3 = __builtin_amdgcn_mfma_f32_16x16x32_bf16(af, cb3, acc3, 0, 0, 0);
        accR = __builtin_amdgcn_mfma_f32_16x16x32_bf16(af, ones, accR, 0, 0, 0);

        ca0 = na0; ca1 = na1;
        cb0 = nb0; cb1 = nb1; cb2 = nb2; cb3 = nb3;
    }

    // cross-wave reduction over the two column halves
    if (jh == 1) {
        f32x4* x = (f32x4*)&xch[pr][l][0];
        x[0] = acc0; x[1] = acc1; x[2] = acc2; x[3] = acc3; x[4] = accR;
    }
    __syncthreads();
    if (jh == 0) {
        const f32x4* x = (const f32x4*)&xch[pr][l][0];
        acc0 += x[0]; acc1 += x[1]; acc2 += x[2]; acc3 += x[3]; accR += x[4];

        float rinv[4];
#pragma unroll
        for (int e = 0; e < 4; e++)
            rinv[e] = accR[e] > 0.f ? 1.f / accR[e] : 0.f;

        float* outp = out + ((size_t)bt * NN + rbase + pr * 16 + q * 4) * FF + m;
#pragma unroll
        for (int e = 0; e < 4; e++) {
            float v0 = acc0[e] * rinv[e];
            float v1 = acc1[e] * rinv[e];
            float v2 = acc2[e] * rinv[e];
            float v3 = acc3[e] * rinv[e];
            v0 = v0 > 0.f ? v0 : expm1f(v0);
            v1 = v1 > 0.f ? v1 : expm1f(v1);
            v2 = v2 > 0.f ? v2 : expm1f(v2);
            v3 = v3 > 0.f ? v3 : expm1f(v3);
            float* o = outp + (size_t)e * FF;
            o[0]  = v0;
            o[16] = v1;
            o[32] = v2;
            o[48] = v3;
        }
    }
}

extern "C" void kernel_launch(void* const* d_in, const int* in_sizes, int n_in,
                              void* d_out, int out_size, void* d_ws, size_t ws_size,
                              hipStream_t stream) {
    const float* h  = (const float*)d_in[0];
    const int*  adj = (const int*)d_in[1];
    const float* W  = (const float*)d_in[2];
    const float* a  = (const float*)d_in[3];
    float* out = (float*)d_out;

    short* WhT = (short*)d_ws;                                      // 64*64*1024*2 = 8 MB
    float* s1  = (float*)((char*)d_ws + (size_t)NBT * FF * NN * 2); // 256 KB
    float* s2  = s1 + NBT * NN;                                     // 256 KB

    k1<<<512, 256, 0, stream>>>(h, W, a, WhT, s1, s2);
    k2<<<2048, 256, 0, stream>>>(adj, WhT, s1, s2, out);
}